// Round 1
// baseline (23173.135 us; speedup 1.0000x reference)
//
#include <hip/hip_runtime.h>
#include <stdint.h>

// Persistent-kernel LSTM, MI355X — R6: tag-in-data sync (counter barrier removed).
//   - h exchanged as f32 with step-tag in mantissa bits [1:0]: (bits & ~3) | (t & 3).
//     Double-buffered by t&1. Consumer poll-loads its region (sc0 sc1) and accepts
//     only when EVERY dword has tag (t-1)&3 — stale (t-3 -> impossible; t-2) data
//     differs in tag bit 1, so the data load IS the barrier (1 LLC round trip).
//     Safety: WG stores slot t&1 only after its step-t poll, which implies all WGs
//     completed their step-(t-1) poll (= finished reading slot t&1). No ABA: step-t+2
//     stores require all step-t+1 stores.
//   - 512-thread WGs: 4 batch-groups x 32 WGs (32 hidden each), 8 waves = 8-way
//     K-split (128 K per wave) -> each WG reads group h (64 KB f32) exactly once
//     per step: 8 MB/step LLC traffic, same as previous bf16 scheme.
//   - Cross-wave partials: ds_add_f32 into padded [4][2][16][17] LDS tile (8.7 KB),
//     zeroed by the reader each step. 2 intra-WG barriers/step, 0 global barriers.
//   - Consumer f32->bf16 MFMA fragments via v_cvt_pk_bf16_f32 (tag bits vanish in
//     the rounding, far below bf16 mantissa).
// ws layout: [0, 512KB) h dbuf (f32-tagged) | [0x80000, +4MB) embW fp32

#define T_STEPS 1024
#define BATCH   64
#define EDIM    256
#define HDIM    1024

typedef float    f32x4  __attribute__((ext_vector_type(4)));
typedef short    bf16x8 __attribute__((ext_vector_type(8)));
typedef uint32_t u32x4  __attribute__((ext_vector_type(4)));

__device__ __forceinline__ unsigned short f2bf(float f) {
  union { float f; uint32_t u; } v; v.f = f;
  uint32_t r = (v.u + 0x7FFFu + ((v.u >> 16) & 1u)) >> 16;  // RNE
  return (unsigned short)r;
}
__device__ __forceinline__ float sigf(float x) { return 1.f / (1.f + __expf(-x)); }
__device__ __forceinline__ float tanh_fast(float x) {
  float ax = fabsf(x);
  float e  = __expf(-2.f * ax);
  float t  = (1.f - e) / (1.f + e);
  return copysignf(t, x);
}

__global__ void __launch_bounds__(256)
embw_kernel(const float* __restrict__ emb, const float* __restrict__ W_ih,
            const float* __restrict__ b_ih, const float* __restrict__ b_hh,
            float* __restrict__ embW)
{
  __shared__ float ev[EDIM];
  const int v   = blockIdx.y;
  const int col = blockIdx.x * 256 + threadIdx.x;
  ev[threadIdx.x] = emb[v * EDIM + threadIdx.x];
  __syncthreads();
  const float4* wr = (const float4*)(W_ih + (size_t)col * EDIM);
  float acc = b_ih[col] + b_hh[col];
#pragma unroll 4
  for (int e4 = 0; e4 < EDIM / 4; ++e4) {
    const float4 q = wr[e4];
    acc += ev[4*e4+0] * q.x + ev[4*e4+1] * q.y + ev[4*e4+2] * q.z + ev[4*e4+3] * q.w;
  }
  embW[(size_t)v * (4 * HDIM) + col] = acc;
}

#define TCHK(R)  do { o |= (R.x ^ tagw); o |= (R.y ^ tagw); \
                      o |= (R.z ^ tagw); o |= (R.w ^ tagw); } while (0)
#define CVTPK(D, A, B) asm("v_cvt_pk_bf16_f32 %0, %1, %2" : "=v"(D) : "v"(A), "v"(B))

__global__ void __launch_bounds__(512, 2)
lstm_kernel(const int* __restrict__ tokens, const int* __restrict__ seq_len,
            const float* __restrict__ W_hh, const float* __restrict__ embW,
            uint32_t* hbuf, float* __restrict__ out)
{
  const int tid = threadIdx.x;
  const int bid = blockIdx.x;     // 0..127
  const int g   = bid & 3;        // batch group (16 samples)
  const int wig = bid >> 2;       // WG within group: 0..31, 32 hidden each
  const int hb  = wig << 5;       // hidden base
  const int gs0 = g << 4;         // sample base
  const int w   = tid >> 6;       // wave 0..7: K-chunk of 128
  const int l   = tid & 63;
  const int lr  = l & 15;         // MFMA m / n index
  const int lq  = l >> 4;         // MFMA k-quad

  // ---- stage W_hh slice into registers as bf16 MFMA B-fragments ----
  bf16x8 bfrag[4][2][4];          // [gate][ntile][kstep]  (128 VGPRs)
#pragma unroll
  for (int n = 0; n < 4; ++n)
#pragma unroll
    for (int nt = 0; nt < 2; ++nt) {
      const float* wrow = W_hh + (size_t)(n * HDIM + hb + nt * 16 + lr) * HDIM
                               + w * 128 + lq * 8;
#pragma unroll
      for (int ks = 0; ks < 4; ++ks) {
        union { bf16x8 v; unsigned short u[8]; } bu;
#pragma unroll
        for (int e = 0; e < 8; ++e) bu.u[e] = f2bf(wrow[ks * 32 + e]);
        bfrag[n][nt][ks] = bu.v;
      }
    }

  const int s  = tid >> 5;        // pointwise: sample-local 0..15
  const int j  = tid & 31;        // pointwise: hidden-local 0..31
  const int b  = gs0 + s;
  const int sl = seq_len[b];
  float c = 0.f, lastc = 0.f;

  __shared__ float part[4][2][16][17];   // [gate][nt][m][n] pad 17

  const uint32_t voff_base = (uint32_t)((gs0 + lr) * (HDIM * 4) + w * 512 + lq * 32);

  for (int t = 0; t < T_STEPS; ++t) {
    // embW gather — independent, overlaps poll latency
    const int tok = tokens[t * BATCH + b];
    const float* er = embW + (size_t)tok * (4 * HDIM) + hb + j;
    float gi = er[0], gf = er[HDIM], gg = er[2 * HDIM], go = er[3 * HDIM];

    if (t > 0) {
      const uint32_t tagw = (uint32_t)((t - 1) & 3);
      const uint32_t voff = ((uint32_t)((t - 1) & 1)) * (BATCH * HDIM * 4u) + voff_base;
      u32x4 r0, r1, r2, r3, r4, r5, r6, r7;
      uint32_t bad;
      do {
        asm volatile(
          "global_load_dwordx4 %0, %8, %9 sc0 sc1\n\t"
          "global_load_dwordx4 %1, %8, %9 offset:16 sc0 sc1\n\t"
          "global_load_dwordx4 %2, %8, %9 offset:128 sc0 sc1\n\t"
          "global_load_dwordx4 %3, %8, %9 offset:144 sc0 sc1\n\t"
          "global_load_dwordx4 %4, %8, %9 offset:256 sc0 sc1\n\t"
          "global_load_dwordx4 %5, %8, %9 offset:272 sc0 sc1\n\t"
          "global_load_dwordx4 %6, %8, %9 offset:384 sc0 sc1\n\t"
          "global_load_dwordx4 %7, %8, %9 offset:400 sc0 sc1\n\t"
          "s_waitcnt vmcnt(0)"
          : "=&v"(r0), "=&v"(r1), "=&v"(r2), "=&v"(r3),
            "=&v"(r4), "=&v"(r5), "=&v"(r6), "=&v"(r7)
          : "v"(voff), "s"(hbuf)
          : "memory");
        uint32_t o = 0;
        TCHK(r0); TCHK(r1); TCHK(r2); TCHK(r3);
        TCHK(r4); TCHK(r5); TCHK(r6); TCHK(r7);
        bad = o & 3u;
      } while (__any(bad != 0));

      // f32 -> bf16 fragments + MFMA
      f32x4 acc[4][2];
#pragma unroll
      for (int n = 0; n < 4; ++n)
#pragma unroll
        for (int nt = 0; nt < 2; ++nt)
          acc[n][nt] = (f32x4){0.f, 0.f, 0.f, 0.f};

      const u32x4 rr[8] = {r0, r1, r2, r3, r4, r5, r6, r7};
#pragma unroll
      for (int ks = 0; ks < 4; ++ks) {
        const u32x4 lo = rr[2 * ks], hi = rr[2 * ks + 1];
        uint32_t q0, q1, q2, q3;
        CVTPK(q0, lo.x, lo.y);
        CVTPK(q1, lo.z, lo.w);
        CVTPK(q2, hi.x, hi.y);
        CVTPK(q3, hi.z, hi.w);
        union { u32x4 u; bf16x8 v; } au;
        au.u = (u32x4){q0, q1, q2, q3};
#pragma unroll
        for (int n = 0; n < 4; ++n)
#pragma unroll
          for (int nt = 0; nt < 2; ++nt)
            acc[n][nt] = __builtin_amdgcn_mfma_f32_16x16x32_bf16(
                au.v, bfrag[n][nt][ks], acc[n][nt], 0, 0, 0);
      }
      // cross-wave K-reduction: LDS float atomics (C layout: col=lane&15,
      // row=(lane>>4)*4+reg)
#pragma unroll
      for (int n = 0; n < 4; ++n)
#pragma unroll
        for (int nt = 0; nt < 2; ++nt)
#pragma unroll
          for (int r = 0; r < 4; ++r)
            atomicAdd(&part[n][nt][lq * 4 + r][lr], acc[n][nt][r]);
    }

    __syncthreads();                       // S1: all waves' adds visible

    const int ntj = j >> 4, nj = j & 15;
    if (t > 0) {
      gi += part[0][ntj][s][nj];
      gf += part[1][ntj][s][nj];
      gg += part[2][ntj][s][nj];
      go += part[3][ntj][s][nj];
    }
    // reader zeroes its own cells for the next step's accumulation
    part[0][ntj][s][nj] = 0.f;
    part[1][ntj][s][nj] = 0.f;
    part[2][ntj][s][nj] = 0.f;
    part[3][ntj][s][nj] = 0.f;

    const float cn = sigf(gf) * c + sigf(gi) * tanh_fast(gg);
    const float hn = sigf(go) * tanh_fast(cn);
    c = cn;
    if ((t == 0) || (t < sl)) lastc = cn;  // freeze mask (step 0 always valid)

    // tagged f32 h store — fire-and-forget, no drain, no counter
    union { float f; uint32_t u; } hv; hv.f = hn;
    const uint32_t tu = (hv.u & ~3u) | (uint32_t)(t & 3);
    __hip_atomic_store(hbuf + (t & 1) * (BATCH * HDIM) + b * HDIM + (hb + j),
                       tu, __ATOMIC_RELAXED, __HIP_MEMORY_SCOPE_AGENT);

    __syncthreads();                       // S2: zeros done before next adds
  }

  out[(size_t)b * HDIM + hb + j] = lastc;
}

extern "C" void kernel_launch(void* const* d_in, const int* in_sizes, int n_in,
                              void* d_out, int out_size, void* d_ws, size_t ws_size,
                              hipStream_t stream) {
  const int*   tokens = (const int*)d_in[0];
  const int*   seqlen = (const int*)d_in[1];
  const float* emb    = (const float*)d_in[2];
  const float* W_ih   = (const float*)d_in[3];
  const float* W_hh   = (const float*)d_in[4];
  const float* b_ih   = (const float*)d_in[5];
  const float* b_hh   = (const float*)d_in[6];
  float* out = (float*)d_out;

  uint8_t*  ws   = (uint8_t*)d_ws;
  uint32_t* hbuf = (uint32_t*)ws;               // 2 * 64*1024 f32 = 512 KB
  float*    embW = (float*)(ws + 0x80000);      // 256 * 4096 fp32 = 4 MB

  // init h dbuf to tag 3 (0xFF bytes): never matches first expected tags 0/1
  hipMemsetAsync(ws, 0xFF, 2 * BATCH * HDIM * 4, stream);
  embw_kernel<<<dim3(16, 256), 256, 0, stream>>>(emb, W_ih, b_ih, b_hh, embW);
  lstm_kernel<<<dim3(128), 512, 0, stream>>>(tokens, seqlen, W_hh, embW, hbuf, out);
}

// Round 2
// 5463.090 us; speedup vs baseline: 4.2418x; 4.2418x over previous
//
#include <hip/hip_runtime.h>
#include <stdint.h>

// Persistent-kernel LSTM, MI355X — R7: R5 skeleton + distributed arrival counters
//                                       + software-pipelined embW gather.
//   - embW[v][col] = emb[v]·W_ih[col] + b_ih[col] + b_hh[col]  (input GEMM == gather)
//   - 256 WGs: 4 batch-groups (16 samples) × 64 WGs (16 hidden each, all 4 gates)
//   - W_hh slice resident in VGPRs as bf16 MFMA B-fragments (128 regs/lane)
//   - h exchange: double-buffered bf16, sc0 sc1 stores/loads (coherence point),
//     8 pipelined dwordx4 loads + single drain (proven R2/R5 path)
//   - R7a sync: 8 arrival counters per group on separate 64B lines (wig&7) ->
//     same-address atomic serialization 64 -> 8 per line. Wave0 polls all 8 via
//     per-octet lane addresses (8 coalesced requests), __any(fv < 8*(t+1)).
//   - R7b pipeline: step-(t+1) embW gather + step-(t+2) token issued between the
//     h store and its vmcnt(0) drain -> gather completes during arrival+poll,
//     removing the post-poll serial gather RTT from the critical path.
//   - LDS partial tile padded to stride 17 (R2: conflict mitigation).
// ws layout: [0,4KB) cnt[4][8] 64B apart | [4096, +256KB) h dbuf | [0x50000, +4MB) embW

#define T_STEPS 1024
#define BATCH   64
#define EDIM    256
#define HDIM    1024

typedef float    f32x4  __attribute__((ext_vector_type(4)));
typedef short    bf16x8 __attribute__((ext_vector_type(8)));
typedef uint32_t u32x4  __attribute__((ext_vector_type(4)));

__device__ __forceinline__ unsigned short f2bf(float f) {
  union { float f; uint32_t u; } v; v.f = f;
  uint32_t r = (v.u + 0x7FFFu + ((v.u >> 16) & 1u)) >> 16;  // RNE
  return (unsigned short)r;
}
__device__ __forceinline__ float sigf(float x) { return 1.f / (1.f + __expf(-x)); }
__device__ __forceinline__ float tanh_fast(float x) {
  float ax = fabsf(x);
  float e  = __expf(-2.f * ax);
  float t  = (1.f - e) / (1.f + e);
  return copysignf(t, x);
}

__global__ void __launch_bounds__(256)
embw_kernel(const float* __restrict__ emb, const float* __restrict__ W_ih,
            const float* __restrict__ b_ih, const float* __restrict__ b_hh,
            float* __restrict__ embW)
{
  __shared__ float ev[EDIM];
  const int v   = blockIdx.y;
  const int col = blockIdx.x * 256 + threadIdx.x;
  ev[threadIdx.x] = emb[v * EDIM + threadIdx.x];
  __syncthreads();
  const float4* wr = (const float4*)(W_ih + (size_t)col * EDIM);
  float acc = b_ih[col] + b_hh[col];
#pragma unroll 4
  for (int e4 = 0; e4 < EDIM / 4; ++e4) {
    const float4 q = wr[e4];
    acc += ev[4*e4+0] * q.x + ev[4*e4+1] * q.y + ev[4*e4+2] * q.z + ev[4*e4+3] * q.w;
  }
  embW[(size_t)v * (4 * HDIM) + col] = acc;
}

__global__ void __launch_bounds__(256, 1)
lstm_kernel(const int* __restrict__ tokens, const int* __restrict__ seq_len,
            const float* __restrict__ W_hh, const float* __restrict__ embW,
            uint32_t* hbuf, uint32_t* cnt, float* __restrict__ out)
{
  const int tid = threadIdx.x;
  const int bid = blockIdx.x;     // 0..255
  const int g   = bid & 3;        // batch group
  const int wig = bid >> 2;       // WG within group: hidden slice
  const int hb  = wig << 4;       // hidden base (16 per WG)
  const int gs0 = g << 4;         // sample base (16 per group)
  const int w   = tid >> 6;       // wave 0..3 (K-split: 256 each)
  const int l   = tid & 63;
  const int lr  = l & 15;         // MFMA m / n index
  const int lq  = l >> 4;         // MFMA k-quad

  // ---- stage W_hh slice into registers as bf16 MFMA B-fragments ----
  bf16x8 bfrag[4][8];             // [gate][kstep]
#pragma unroll
  for (int n = 0; n < 4; ++n) {
    const float* wrow = W_hh + (size_t)(n * HDIM + hb + lr) * HDIM + w * 256 + lq * 8;
#pragma unroll
    for (int ks = 0; ks < 8; ++ks) {
      union { bf16x8 v; unsigned short u[8]; } bu;
#pragma unroll
      for (int e = 0; e < 8; ++e) bu.u[e] = f2bf(wrow[ks * 32 + e]);
      bfrag[n][ks] = bu.v;
    }
  }

  const int s  = tid >> 4;        // pointwise: sample-local
  const int j  = tid & 15;        // pointwise: hidden-local
  const int b  = gs0 + s;
  const int sl = seq_len[b];
  float c = 0.f, lastc = 0.f;

  __shared__ float part[4][4][16][17];   // [wave][gate][m][n] pad 17

  const uint32_t voff_base = (uint32_t)((gs0 + lr) * (HDIM * 2) + (w * 512 + lq * 16));

  // ---- gather pipeline preload: step 0 gather (blocking) + step 1 token ----
  const int tok0 = tokens[b];
  {
    // touch nothing else; plain cached loads
  }
  const float* er0 = embW + (size_t)tok0 * (4 * HDIM) + hb + j;
  float gi = er0[0], gf = er0[HDIM], gg = er0[2 * HDIM], go = er0[3 * HDIM];
  int tok_n = tokens[BATCH + b];            // token for step 1 (T_STEPS >= 2)

  for (int t = 0; t < T_STEPS; ++t) {
    if (t > 0) {
      const uint32_t voff = ((uint32_t)((t - 1) & 1)) * (BATCH * HDIM * 2) + voff_base;
      u32x4 r0, r1, r2, r3, r4, r5, r6, r7;
      // 8 pipelined cache-bypassing 16B loads + single drain (proven R2 path)
      asm volatile(
        "global_load_dwordx4 %0, %8, %9 sc0 sc1\n\t"
        "global_load_dwordx4 %1, %8, %9 offset:64 sc0 sc1\n\t"
        "global_load_dwordx4 %2, %8, %9 offset:128 sc0 sc1\n\t"
        "global_load_dwordx4 %3, %8, %9 offset:192 sc0 sc1\n\t"
        "global_load_dwordx4 %4, %8, %9 offset:256 sc0 sc1\n\t"
        "global_load_dwordx4 %5, %8, %9 offset:320 sc0 sc1\n\t"
        "global_load_dwordx4 %6, %8, %9 offset:384 sc0 sc1\n\t"
        "global_load_dwordx4 %7, %8, %9 offset:448 sc0 sc1\n\t"
        "s_waitcnt vmcnt(0)"
        : "=&v"(r0), "=&v"(r1), "=&v"(r2), "=&v"(r3),
          "=&v"(r4), "=&v"(r5), "=&v"(r6), "=&v"(r7)
        : "v"(voff), "s"(hbuf)
        : "memory");

      u32x4 areg[8] = {r0, r1, r2, r3, r4, r5, r6, r7};
      f32x4 a0 = {0.f,0.f,0.f,0.f}, a1 = a0, a2 = a0, a3 = a0;
#pragma unroll
      for (int ks = 0; ks < 8; ++ks) {
        union { bf16x8 v; u32x4 u; } au;
        au.u = areg[ks];
        a0 = __builtin_amdgcn_mfma_f32_16x16x32_bf16(au.v, bfrag[0][ks], a0, 0, 0, 0);
        a1 = __builtin_amdgcn_mfma_f32_16x16x32_bf16(au.v, bfrag[1][ks], a1, 0, 0, 0);
        a2 = __builtin_amdgcn_mfma_f32_16x16x32_bf16(au.v, bfrag[2][ks], a2, 0, 0, 0);
        a3 = __builtin_amdgcn_mfma_f32_16x16x32_bf16(au.v, bfrag[3][ks], a3, 0, 0, 0);
      }
#pragma unroll
      for (int r = 0; r < 4; ++r) {        // C layout: col=lane&15, row=(lane>>4)*4+reg
        const int m = lq * 4 + r;
        part[w][0][m][lr] = a0[r];
        part[w][1][m][lr] = a1[r];
        part[w][2][m][lr] = a2[r];
        part[w][3][m][lr] = a3[r];
      }
    }
    __syncthreads();

    if (t > 0) {
#pragma unroll
      for (int ww = 0; ww < 4; ++ww) {
        gi += part[ww][0][s][j];
        gf += part[ww][1][s][j];
        gg += part[ww][2][s][j];
        go += part[ww][3][s][j];
      }
    }

    const float cn = sigf(gf) * c + sigf(gi) * tanh_fast(gg);
    const float hn = sigf(go) * tanh_fast(cn);
    c = cn;
    if ((t == 0) || (t < sl)) lastc = cn;   // freeze mask (step 0 always valid)

    // h -> bf16 pair -> store to coherence point
    const unsigned short hu = f2bf(hn);
    const int other = __shfl_xor((int)hu, 1);
    if ((j & 1) == 0) {
      const uint32_t pk = (uint32_t)hu | ((uint32_t)(unsigned short)other << 16);
      __hip_atomic_store(hbuf + (t & 1) * (BATCH * HDIM / 2) + b * (HDIM / 2) + ((hb + j) >> 1),
                         pk, __ATOMIC_RELAXED, __HIP_MEMORY_SCOPE_AGENT);
    }

    // ---- R7b: prefetch step-(t+1) gather + step-(t+2) token; these ride the
    // same vmcnt(0) the store-ack pays and complete during arrival+poll ----
    const float* ern = embW + (size_t)tok_n * (4 * HDIM) + hb + j;
    const float ngi = ern[0], ngf = ern[HDIM], ngg = ern[2 * HDIM], ngo = ern[3 * HDIM];
    const int t2 = (t + 2 < T_STEPS) ? (t + 2) : 0;
    const int tok_n2 = tokens[t2 * BATCH + b];

    asm volatile("s_waitcnt vmcnt(0)" ::: "memory");  // per-wave drain: h acked
    __syncthreads();                                  // => ALL waves' h acked

    if (t + 1 < T_STEPS) {
      // R7a: arrival on distributed counter line (wig&7) — fire-and-forget
      if (tid == 0)
        __hip_atomic_fetch_add(cnt + (g * 8 + (wig & 7)) * 16, 1u,
                               __ATOMIC_RELAXED, __HIP_MEMORY_SCOPE_AGENT);
      if (w == 0) {
        // wave 0 polls all 8 counters: lane octet l>>3 -> counter line (coalesced
        // to 8 requests), single-outstanding lazy rate (proven contention-safe)
        const uint32_t target = (uint32_t)(8 * (t + 1));
        const uint32_t coff = (uint32_t)((g * 8 + (l >> 3)) * 64);
        uint32_t fv;
        do {
          asm volatile("global_load_dword %0, %1, %2 sc0 sc1\n\ts_waitcnt vmcnt(0)"
                       : "=v"(fv) : "v"(coff), "s"(cnt) : "memory");
        } while (__any(fv < target));
      }
      __syncthreads();
    }

    // rotate gather pipeline
    gi = ngi; gf = ngf; gg = ngg; go = ngo;
    tok_n = tok_n2;
  }

  out[(size_t)b * HDIM + hb + j] = lastc;
}

extern "C" void kernel_launch(void* const* d_in, const int* in_sizes, int n_in,
                              void* d_out, int out_size, void* d_ws, size_t ws_size,
                              hipStream_t stream) {
  const int*   tokens = (const int*)d_in[0];
  const int*   seqlen = (const int*)d_in[1];
  const float* emb    = (const float*)d_in[2];
  const float* W_ih   = (const float*)d_in[3];
  const float* W_hh   = (const float*)d_in[4];
  const float* b_ih   = (const float*)d_in[5];
  const float* b_hh   = (const float*)d_in[6];
  float* out = (float*)d_out;

  uint8_t*  ws    = (uint8_t*)d_ws;
  uint32_t* cnt   = (uint32_t*)ws;                  // 4 groups x 8 counters, 64B apart
  uint32_t* hbuf  = (uint32_t*)(ws + 4096);         // 2 * 64*1024 bf16 = 256 KB
  float*    embW  = (float*)(ws + 0x50000);         // 256 * 4096 fp32 = 4 MB

  hipMemsetAsync(ws, 0, 4096, stream);              // zero arrival counters every launch
  embw_kernel<<<dim3(16, 256), 256, 0, stream>>>(emb, W_ih, b_ih, b_hh, embW);
  lstm_kernel<<<dim3(256), 256, 0, stream>>>(tokens, seqlen, W_hh, embW, hbuf, cnt, out);
}

// Round 3
// 4145.168 us; speedup vs baseline: 5.5904x; 1.3179x over previous
//
#include <hip/hip_runtime.h>
#include <stdint.h>

// Persistent-kernel LSTM, MI355X — R8: halve coherent h-broadcast traffic.
//   Model (fits R5/R6/R7): step time ≈ coherent bytes / ~2 TB/s LLC coherent BW.
//   - 128 WGs x 512 threads: 4 batch-groups x 32 WGs (32 hidden each, all 4 gates)
//     -> h broadcast redundancy 64 -> 32 readers: 8 MB -> 4 MB per step.
//   - 8-wave K-split (128 K per wave, 4 ksteps); W_hh slice in VGPRs as bf16
//     B-fragments bfrag[4][2][4] = 128 regs/lane (same per-lane budget as R5).
//   - Sync: EXACT R5 scheme (proven stable): one counter per group, tid0
//     fire-and-forget atomicAdd, wave0 single-dword sc0 sc1 lazy poll,
//     target 32*(t+1). (R7's 8-line poll reverted: +2MB/step traffic + outliers.)
//   - R7b kept: step-(t+1) embW gather + step-(t+2) token prefetched between the
//     h store and its vmcnt(0) drain (rides the same drain, completes under poll).
//   - Cross-wave partials: part[8][4][2][16][18] (73.7 KB LDS); pad 18 -> inter-lq
//     bank stride 8 mod 32 -> 2-way (free) instead of 4-way conflicts.
// ws layout: [0,4KB) cnt[4] 64B apart | [4096, +256KB) h dbuf bf16 | [0x50000, +4MB) embW

#define T_STEPS 1024
#define BATCH   64
#define EDIM    256
#define HDIM    1024

typedef float    f32x4  __attribute__((ext_vector_type(4)));
typedef short    bf16x8 __attribute__((ext_vector_type(8)));
typedef uint32_t u32x4  __attribute__((ext_vector_type(4)));

__device__ __forceinline__ unsigned short f2bf(float f) {
  union { float f; uint32_t u; } v; v.f = f;
  uint32_t r = (v.u + 0x7FFFu + ((v.u >> 16) & 1u)) >> 16;  // RNE
  return (unsigned short)r;
}
__device__ __forceinline__ float sigf(float x) { return 1.f / (1.f + __expf(-x)); }
__device__ __forceinline__ float tanh_fast(float x) {
  float ax = fabsf(x);
  float e  = __expf(-2.f * ax);
  float t  = (1.f - e) / (1.f + e);
  return copysignf(t, x);
}

__global__ void __launch_bounds__(256)
embw_kernel(const float* __restrict__ emb, const float* __restrict__ W_ih,
            const float* __restrict__ b_ih, const float* __restrict__ b_hh,
            float* __restrict__ embW)
{
  __shared__ float ev[EDIM];
  const int v   = blockIdx.y;
  const int col = blockIdx.x * 256 + threadIdx.x;
  ev[threadIdx.x] = emb[v * EDIM + threadIdx.x];
  __syncthreads();
  const float4* wr = (const float4*)(W_ih + (size_t)col * EDIM);
  float acc = b_ih[col] + b_hh[col];
#pragma unroll 4
  for (int e4 = 0; e4 < EDIM / 4; ++e4) {
    const float4 q = wr[e4];
    acc += ev[4*e4+0] * q.x + ev[4*e4+1] * q.y + ev[4*e4+2] * q.z + ev[4*e4+3] * q.w;
  }
  embW[(size_t)v * (4 * HDIM) + col] = acc;
}

__global__ void __launch_bounds__(512, 1)
lstm_kernel(const int* __restrict__ tokens, const int* __restrict__ seq_len,
            const float* __restrict__ W_hh, const float* __restrict__ embW,
            uint32_t* hbuf, uint32_t* cnt, float* __restrict__ out)
{
  const int tid = threadIdx.x;
  const int bid = blockIdx.x;     // 0..127
  const int g   = bid & 3;        // batch group
  const int wig = bid >> 2;       // WG within group: 0..31
  const int hb  = wig << 5;       // hidden base (32 per WG)
  const int gs0 = g << 4;         // sample base (16 per group)
  const int w   = tid >> 6;       // wave 0..7 (K-split: 128 each)
  const int l   = tid & 63;
  const int lr  = l & 15;         // MFMA m / n index
  const int lq  = l >> 4;         // MFMA k-quad

  // ---- stage W_hh slice into registers as bf16 MFMA B-fragments ----
  bf16x8 bfrag[4][2][4];          // [gate][ntile][kstep] = 128 VGPRs
#pragma unroll
  for (int n = 0; n < 4; ++n)
#pragma unroll
    for (int nt = 0; nt < 2; ++nt) {
      const float* wrow = W_hh + (size_t)(n * HDIM + hb + nt * 16 + lr) * HDIM
                               + w * 128 + lq * 8;
#pragma unroll
      for (int ks = 0; ks < 4; ++ks) {
        union { bf16x8 v; unsigned short u[8]; } bu;
#pragma unroll
        for (int e = 0; e < 8; ++e) bu.u[e] = f2bf(wrow[ks * 32 + e]);
        bfrag[n][nt][ks] = bu.v;
      }
    }

  const int s  = tid >> 5;        // pointwise: sample-local 0..15
  const int j  = tid & 31;        // pointwise: hidden-local 0..31
  const int b  = gs0 + s;
  const int sl = seq_len[b];
  float c = 0.f, lastc = 0.f;

  __shared__ float part[8][4][2][16][18];  // [wave][gate][nt][m][n] pad 18

  uint32_t* cnt_g = cnt + g * 16;          // 64B-separated per-group counter line

  const uint32_t voff_base = (uint32_t)((gs0 + lr) * (HDIM * 2) + w * 256 + lq * 16);

  // ---- gather pipeline preload: step 0 gather (blocking) + step 1 token ----
  const int tok0 = tokens[b];
  const float* er0 = embW + (size_t)tok0 * (4 * HDIM) + hb + j;
  float gi = er0[0], gf = er0[HDIM], gg = er0[2 * HDIM], go = er0[3 * HDIM];
  int tok_n = tokens[BATCH + b];           // token for step 1

  for (int t = 0; t < T_STEPS; ++t) {
    if (t > 0) {
      const uint32_t voff = ((uint32_t)((t - 1) & 1)) * (BATCH * HDIM * 2) + voff_base;
      u32x4 r0, r1, r2, r3;
      // 4 pipelined cache-bypassing 16B loads + single drain (R2-proven path)
      asm volatile(
        "global_load_dwordx4 %0, %4, %5 sc0 sc1\n\t"
        "global_load_dwordx4 %1, %4, %5 offset:64 sc0 sc1\n\t"
        "global_load_dwordx4 %2, %4, %5 offset:128 sc0 sc1\n\t"
        "global_load_dwordx4 %3, %4, %5 offset:192 sc0 sc1\n\t"
        "s_waitcnt vmcnt(0)"
        : "=&v"(r0), "=&v"(r1), "=&v"(r2), "=&v"(r3)
        : "v"(voff), "s"(hbuf)
        : "memory");

      u32x4 areg[4] = {r0, r1, r2, r3};
      f32x4 acc[4][2];
#pragma unroll
      for (int n = 0; n < 4; ++n)
#pragma unroll
        for (int nt = 0; nt < 2; ++nt)
          acc[n][nt] = (f32x4){0.f, 0.f, 0.f, 0.f};
#pragma unroll
      for (int ks = 0; ks < 4; ++ks) {
        union { bf16x8 v; u32x4 u; } au;
        au.u = areg[ks];
#pragma unroll
        for (int n = 0; n < 4; ++n)
#pragma unroll
          for (int nt = 0; nt < 2; ++nt)
            acc[n][nt] = __builtin_amdgcn_mfma_f32_16x16x32_bf16(
                au.v, bfrag[n][nt][ks], acc[n][nt], 0, 0, 0);
      }
#pragma unroll
      for (int n = 0; n < 4; ++n)
#pragma unroll
        for (int nt = 0; nt < 2; ++nt)
#pragma unroll
          for (int r = 0; r < 4; ++r)   // C layout: col=lane&15, row=(lane>>4)*4+reg
            part[w][n][nt][lq * 4 + r][lr] = acc[n][nt][r];
    }
    __syncthreads();

    if (t > 0) {
      const int ntj = j >> 4, nj = j & 15;
#pragma unroll
      for (int ww = 0; ww < 8; ++ww) {
        gi += part[ww][0][ntj][s][nj];
        gf += part[ww][1][ntj][s][nj];
        gg += part[ww][2][ntj][s][nj];
        go += part[ww][3][ntj][s][nj];
      }
    }

    const float cn = sigf(gf) * c + sigf(gi) * tanh_fast(gg);
    const float hn = sigf(go) * tanh_fast(cn);
    c = cn;
    if ((t == 0) || (t < sl)) lastc = cn;   // freeze mask (step 0 always valid)

    // h -> bf16 pair -> store to coherence point
    const unsigned short hu = f2bf(hn);
    const int other = __shfl_xor((int)hu, 1);
    if ((j & 1) == 0) {
      const uint32_t pk = (uint32_t)hu | ((uint32_t)(unsigned short)other << 16);
      __hip_atomic_store(hbuf + (t & 1) * (BATCH * HDIM / 2) + b * (HDIM / 2) + ((hb + j) >> 1),
                         pk, __ATOMIC_RELAXED, __HIP_MEMORY_SCOPE_AGENT);
    }

    // ---- prefetch step-(t+1) gather + step-(t+2) token; these ride the same
    // vmcnt(0) the store-ack pays and complete during arrival+poll ----
    const float* ern = embW + (size_t)tok_n * (4 * HDIM) + hb + j;
    const float ngi = ern[0], ngf = ern[HDIM], ngg = ern[2 * HDIM], ngo = ern[3 * HDIM];
    const int t2 = (t + 2 < T_STEPS) ? (t + 2) : 0;
    const int tok_n2 = tokens[t2 * BATCH + b];

    asm volatile("s_waitcnt vmcnt(0)" ::: "memory");  // per-wave drain: h acked
    __syncthreads();                                  // => ALL waves' h acked

    if (t + 1 < T_STEPS) {
      // arrival: one fire-and-forget add per WG (result unused -> no wait)
      if (tid == 0)
        __hip_atomic_fetch_add(cnt_g, 1u, __ATOMIC_RELAXED, __HIP_MEMORY_SCOPE_AGENT);
      if (w == 0) {
        // wave 0 polls ONE dword (all lanes same addr -> 1 coalesced request)
        const uint32_t target = (uint32_t)(32 * (t + 1));
        uint32_t fv;
        do {
          asm volatile("global_load_dword %0, %1, %2 sc0 sc1\n\ts_waitcnt vmcnt(0)"
                       : "=v"(fv) : "v"(0u), "s"(cnt_g) : "memory");
        } while (fv < target);
      }
      __syncthreads();
    }

    // rotate gather pipeline
    gi = ngi; gf = ngf; gg = ngg; go = ngo;
    tok_n = tok_n2;
  }

  out[(size_t)b * HDIM + hb + j] = lastc;
}

extern "C" void kernel_launch(void* const* d_in, const int* in_sizes, int n_in,
                              void* d_out, int out_size, void* d_ws, size_t ws_size,
                              hipStream_t stream) {
  const int*   tokens = (const int*)d_in[0];
  const int*   seqlen = (const int*)d_in[1];
  const float* emb    = (const float*)d_in[2];
  const float* W_ih   = (const float*)d_in[3];
  const float* W_hh   = (const float*)d_in[4];
  const float* b_ih   = (const float*)d_in[5];
  const float* b_hh   = (const float*)d_in[6];
  float* out = (float*)d_out;

  uint8_t*  ws    = (uint8_t*)d_ws;
  uint32_t* cnt   = (uint32_t*)ws;                  // 4 counters, 64B apart
  uint32_t* hbuf  = (uint32_t*)(ws + 4096);         // 2 * 64*1024 bf16 = 256 KB
  float*    embW  = (float*)(ws + 0x50000);         // 256 * 4096 fp32 = 4 MB

  hipMemsetAsync(ws, 0, 4096, stream);              // zero arrival counters every launch
  embw_kernel<<<dim3(16, 256), 256, 0, stream>>>(emb, W_ih, b_ih, b_hh, embW);
  lstm_kernel<<<dim3(128), 512, 0, stream>>>(tokens, seqlen, W_hh, embW, hbuf, cnt, out);
}

// Round 6
// 3733.327 us; speedup vs baseline: 6.2071x; 1.1103x over previous
//
#include <hip/hip_runtime.h>
#include <stdint.h>

// Persistent-kernel LSTM, MI355X — R11: tag-in-data sync, compiler-safe form.
//   R10 hang root-cause: speculative loads' result registers lived in C vars
//   across barriers/loop backedge -> regalloc may move them while the load is
//   in flight -> poll reads a dead copy -> livelock. R11 keeps every load and
//   its s_waitcnt inside ONE asm region (R6-proven pattern + masked retry).
//   - h exchange: f32, 1-bit step tag in mantissa LSB. Slot = t&1, tag =
//     (t>>1)&1 distinguishes t from t-2. The data load IS the barrier: no
//     counter, no atomicAdd, no producer-side vmcnt drain.
//     Safety: WG X overwrites slot t&1 (h(t) -> h(t+2)) only after X passed
//     its step-(t+2) poll => all WGs stored h(t+1) => all passed step-(t+1)
//     poll => all hold h(t) in registers. No ABA.
//   - Retry: per-LANE exec-masked (only stale lanes re-issue their 128 B);
//     converging mask -> no R6-style storm.
//   - Barriers WITHOUT vmcnt drains (lgkmcnt(0) + s_barrier + sched_barrier):
//     h store is fire-and-forget; next step's poll vmcnt(0) is the only drain.
//   - Gather: embW loads issued before the poll; the poll's vmcnt(0) covers
//     them, so gather latency hides under the first (always-stale) attempt.
//   - Geometry = R8: 128 WGs x 512 thr, 4 groups x 32 WGs (32 hidden each),
//     8-wave K-split (128 K/wave), bfrag[4][2][4] = 128 VGPRs.
//   - LDS partials: part[8][4][2][16][17], pad 17.
// ws layout: [0, 512KB) h dbuf (f32-tagged) | [0x80000, +4MB) embW fp32

#define T_STEPS 1024
#define BATCH   64
#define EDIM    256
#define HDIM    1024

typedef float    f32x4  __attribute__((ext_vector_type(4)));
typedef short    bf16x8 __attribute__((ext_vector_type(8)));
typedef uint32_t u32x4  __attribute__((ext_vector_type(4)));

__device__ __forceinline__ unsigned short f2bf(float f) {
  union { float f; uint32_t u; } v; v.f = f;
  uint32_t r = (v.u + 0x7FFFu + ((v.u >> 16) & 1u)) >> 16;  // RNE
  return (unsigned short)r;
}
__device__ __forceinline__ float sigf(float x) { return 1.f / (1.f + __expf(-x)); }
__device__ __forceinline__ float tanh_fast(float x) {
  float ax = fabsf(x);
  float e  = __expf(-2.f * ax);
  float t  = (1.f - e) / (1.f + e);
  return copysignf(t, x);
}

__global__ void __launch_bounds__(256)
embw_kernel(const float* __restrict__ emb, const float* __restrict__ W_ih,
            const float* __restrict__ b_ih, const float* __restrict__ b_hh,
            float* __restrict__ embW)
{
  __shared__ float ev[EDIM];
  const int v   = blockIdx.y;
  const int col = blockIdx.x * 256 + threadIdx.x;
  ev[threadIdx.x] = emb[v * EDIM + threadIdx.x];
  __syncthreads();
  const float4* wr = (const float4*)(W_ih + (size_t)col * EDIM);
  float acc = b_ih[col] + b_hh[col];
#pragma unroll 4
  for (int e4 = 0; e4 < EDIM / 4; ++e4) {
    const float4 q = wr[e4];
    acc += ev[4*e4+0] * q.x + ev[4*e4+1] * q.y + ev[4*e4+2] * q.z + ev[4*e4+3] * q.w;
  }
  embW[(size_t)v * (4 * HDIM) + col] = acc;
}

// 8 coherent 16B loads + in-asm drain. "+v" ties outputs so exec-masked lanes
// keep their previous (fresh) values across retries. Load AND wait live in one
// asm region: no in-flight registers ever cross C statements.
#define ISSUE8_WAIT(VOFF)                                                   \
  asm volatile(                                                             \
    "global_load_dwordx4 %0, %8, %9 sc0 sc1\n\t"                            \
    "global_load_dwordx4 %1, %8, %9 offset:16 sc0 sc1\n\t"                  \
    "global_load_dwordx4 %2, %8, %9 offset:128 sc0 sc1\n\t"                 \
    "global_load_dwordx4 %3, %8, %9 offset:144 sc0 sc1\n\t"                 \
    "global_load_dwordx4 %4, %8, %9 offset:256 sc0 sc1\n\t"                 \
    "global_load_dwordx4 %5, %8, %9 offset:272 sc0 sc1\n\t"                 \
    "global_load_dwordx4 %6, %8, %9 offset:384 sc0 sc1\n\t"                 \
    "global_load_dwordx4 %7, %8, %9 offset:400 sc0 sc1\n\t"                 \
    "s_waitcnt vmcnt(0)"                                                    \
    : "+v"(r0), "+v"(r1), "+v"(r2), "+v"(r3),                               \
      "+v"(r4), "+v"(r5), "+v"(r6), "+v"(r7)                                \
    : "v"(VOFF), "s"(hbuf)                                                  \
    : "memory")

#define TCHK(R) do { o |= (R.x ^ tagw); o |= (R.y ^ tagw);                  \
                     o |= (R.z ^ tagw); o |= (R.w ^ tagw); } while (0)

// freshness sweep over all 8 result registers -> bad (per-lane, LSB only)
#define TAGCHK8() do { o = 0;                                               \
    TCHK(r0); TCHK(r1); TCHK(r2); TCHK(r3);                                 \
    TCHK(r4); TCHK(r5); TCHK(r6); TCHK(r7);                                 \
    bad = o & 1u; } while (0)

#define CVTPK(D, A, B) asm("v_cvt_pk_bf16_f32 %0, %1, %2" : "=v"(D) : "v"(A), "v"(B))

// LDS-only barrier: order ds ops, leave VMEM (the h store) in flight.
#define LDS_BARRIER() do {                                                  \
    asm volatile("s_waitcnt lgkmcnt(0)" ::: "memory");                      \
    __builtin_amdgcn_s_barrier();                                           \
    __builtin_amdgcn_sched_barrier(0);                                      \
  } while (0)

__global__ void __launch_bounds__(512, 1)
lstm_kernel(const int* __restrict__ tokens, const int* __restrict__ seq_len,
            const float* __restrict__ W_hh, const float* __restrict__ embW,
            uint32_t* hbuf, float* __restrict__ out)
{
  const int tid = threadIdx.x;
  const int bid = blockIdx.x;     // 0..127
  const int g   = bid & 3;        // batch group
  const int wig = bid >> 2;       // WG within group: 0..31
  const int hb  = wig << 5;       // hidden base (32 per WG)
  const int gs0 = g << 4;         // sample base (16 per group)
  const int w   = tid >> 6;       // wave 0..7 (K-split: 128 each)
  const int l   = tid & 63;
  const int lr  = l & 15;         // MFMA m / n index
  const int lq  = l >> 4;         // MFMA k-quad

  // ---- stage W_hh slice into registers as bf16 MFMA B-fragments ----
  bf16x8 bfrag[4][2][4];          // [gate][ntile][kstep] = 128 VGPRs
#pragma unroll
  for (int n = 0; n < 4; ++n)
#pragma unroll
    for (int nt = 0; nt < 2; ++nt) {
      const float* wrow = W_hh + (size_t)(n * HDIM + hb + nt * 16 + lr) * HDIM
                               + w * 128 + lq * 8;
#pragma unroll
      for (int ks = 0; ks < 4; ++ks) {
        union { bf16x8 v; unsigned short u[8]; } bu;
#pragma unroll
        for (int e = 0; e < 8; ++e) bu.u[e] = f2bf(wrow[ks * 32 + e]);
        bfrag[n][nt][ks] = bu.v;
      }
    }

  const int s  = tid >> 5;        // pointwise: sample-local 0..15
  const int j  = tid & 31;        // pointwise: hidden-local 0..31
  const int b  = gs0 + s;
  const int sl = seq_len[b];
  float c = 0.f, lastc = 0.f;

  __shared__ float part[8][4][2][16][17];  // [wave][gate][nt][m][n] pad 17 (69.6 KB)

  // f32 h: lane (w,lq,lr) reads h[gs0+lr][w*128 + ks*32 + lq*8 .. +8)
  const uint32_t voff_base = (uint32_t)(((gs0 + lr) * HDIM + w * 128 + lq * 8) * 4);

  int tok = tokens[b];            // token for step 0

  for (int t = 0; t < T_STEPS; ++t) {
    // ---- embW gather for step t (plain cached loads). Issued BEFORE the
    // poll; the poll's vmcnt(0) covers them -> latency hides under attempt 1.
    const float* er = embW + (size_t)tok * (4 * HDIM) + hb + j;
    float gi = er[0], gf = er[HDIM], gg = er[2 * HDIM], go = er[3 * HDIM];
    const int tnext = (t + 1 < T_STEPS) ? (t + 1) : t;
    const int tok_n = tokens[tnext * BATCH + b];

    if (t > 0) {
      const uint32_t tagw = (uint32_t)(((t - 1) >> 1) & 1);
      const uint32_t voff = ((uint32_t)((t - 1) & 1)) * (BATCH * HDIM * 4u) + voff_base;
      u32x4 r0 = {0,0,0,0}, r1 = r0, r2 = r0, r3 = r0,
            r4 = r0, r5 = r0, r6 = r0, r7 = r0;
      uint32_t o, bad;
      ISSUE8_WAIT(voff);
      TAGCHK8();
      while (__any(bad != 0)) {
        if (bad != 0) {                    // per-lane masked retry: stale lanes only
          ISSUE8_WAIT(voff);
          TAGCHK8();
        }
      }

      // f32 -> bf16 fragments + MFMA
      f32x4 acc[4][2];
#pragma unroll
      for (int n = 0; n < 4; ++n)
#pragma unroll
        for (int nt = 0; nt < 2; ++nt)
          acc[n][nt] = (f32x4){0.f, 0.f, 0.f, 0.f};

      const u32x4 rr[8] = {r0, r1, r2, r3, r4, r5, r6, r7};
#pragma unroll
      for (int ks = 0; ks < 4; ++ks) {
        const u32x4 lo = rr[2 * ks], hi = rr[2 * ks + 1];
        uint32_t q0, q1, q2, q3;
        CVTPK(q0, __uint_as_float(lo.x), __uint_as_float(lo.y));
        CVTPK(q1, __uint_as_float(lo.z), __uint_as_float(lo.w));
        CVTPK(q2, __uint_as_float(hi.x), __uint_as_float(hi.y));
        CVTPK(q3, __uint_as_float(hi.z), __uint_as_float(hi.w));
        union { u32x4 u; bf16x8 v; } au;
        au.u = (u32x4){q0, q1, q2, q3};
#pragma unroll
        for (int n = 0; n < 4; ++n)
#pragma unroll
          for (int nt = 0; nt < 2; ++nt)
            acc[n][nt] = __builtin_amdgcn_mfma_f32_16x16x32_bf16(
                au.v, bfrag[n][nt][ks], acc[n][nt], 0, 0, 0);
      }
#pragma unroll
      for (int n = 0; n < 4; ++n)
#pragma unroll
        for (int nt = 0; nt < 2; ++nt)
#pragma unroll
          for (int r = 0; r < 4; ++r)   // C layout: col=lane&15, row=(lane>>4)*4+reg
            part[w][n][nt][lq * 4 + r][lr] = acc[n][nt][r];
    }

    LDS_BARRIER();                       // S1: partial writes visible (no vmcnt drain)

    if (t > 0) {
      const int ntj = j >> 4, nj = j & 15;
#pragma unroll
      for (int ww = 0; ww < 8; ++ww) {
        gi += part[ww][0][ntj][s][nj];
        gf += part[ww][1][ntj][s][nj];
        gg += part[ww][2][ntj][s][nj];
        go += part[ww][3][ntj][s][nj];
      }
    }

    const float cn = sigf(gf) * c + sigf(gi) * tanh_fast(gg);
    const float hn = sigf(go) * tanh_fast(cn);
    c = cn;
    if ((t == 0) || (t < sl)) lastc = cn;   // freeze mask (step 0 always valid)

    // tagged f32 h store — fire-and-forget, no drain, no counter
    union { float f; uint32_t u; } hv; hv.f = hn;
    const uint32_t tu = (hv.u & ~1u) | (uint32_t)((t >> 1) & 1);
    __hip_atomic_store(hbuf + (t & 1) * (BATCH * HDIM) + b * HDIM + (hb + j),
                       tu, __ATOMIC_RELAXED, __HIP_MEMORY_SCOPE_AGENT);

    LDS_BARRIER();                       // S2: partial reads done before next writes

    tok = tok_n;
  }

  out[(size_t)b * HDIM + hb + j] = lastc;
}

extern "C" void kernel_launch(void* const* d_in, const int* in_sizes, int n_in,
                              void* d_out, int out_size, void* d_ws, size_t ws_size,
                              hipStream_t stream) {
  const int*   tokens = (const int*)d_in[0];
  const int*   seqlen = (const int*)d_in[1];
  const float* emb    = (const float*)d_in[2];
  const float* W_ih   = (const float*)d_in[3];
  const float* W_hh   = (const float*)d_in[4];
  const float* b_ih   = (const float*)d_in[5];
  const float* b_hh   = (const float*)d_in[6];
  float* out = (float*)d_out;

  uint8_t*  ws   = (uint8_t*)d_ws;
  uint32_t* hbuf = (uint32_t*)ws;               // 2 * 64*1024 f32 = 512 KB
  float*    embW = (float*)(ws + 0x80000);      // 256 * 4096 fp32 = 4 MB

  // init h dbuf to 0xFF: LSB=1 != first expected tag (0) for both slots' first use
  hipMemsetAsync(ws, 0xFF, 2 * BATCH * HDIM * 4, stream);
  embw_kernel<<<dim3(16, 256), 256, 0, stream>>>(emb, W_ih, b_ih, b_hh, embW);
  lstm_kernel<<<dim3(128), 512, 0, stream>>>(tokens, seqlen, W_hh, embW, hbuf, out);
}

// Round 8
// 3055.386 us; speedup vs baseline: 7.5844x; 1.2219x over previous
//
#include <hip/hip_runtime.h>
#include <stdint.h>

// Persistent-kernel LSTM, MI355X — R13: R11 structure + bf16-packed tagged h.
//   R12 lesson: exact-capacity persistent launches (1 WG/CU, 256 WGs) can
//   deadlock on placement — never launch a spin-protocol at zero slack.
//   R13 is the byte-halving A/B on the PROVEN R11 skeleton:
//   - h exchange: u32 = 2 x bf16 (R5's pairing), tag bit = u32 LSB (low
//     element's mantissa LSB). Slot t&1, tag (t>>1)&1 distinguishes t vs t-2.
//     The data load IS the barrier (R11-proven): no counter, no atomicAdd,
//     no producer drain. Loads double as MFMA A-fragments (no cvt_pk).
//   - Poll: 4 x dwordx4 per lane (16KB/WG/attempt, half of R11), load+wait in
//     ONE asm region (R10 lesson), per-lane exec-masked retry (R6 lesson).
//   - Barriers without vmcnt drains: lgkmcnt(0) + s_barrier + sched_barrier.
//   - Geometry = R11: 128 WGs x 512 thr (>=2x co-residency slack), 4 groups x
//     32 WGs (32 hidden each), 8-wave K-split (128 K/wave), bfrag = 128 VGPRs.
//   - LDS partials: part[8][4][2][16][17], pad 17.
//   A/B readout: dur unchanged => latency-chain confirmed -> XCD-local next;
//   dur -400us+ => byte-queueing real -> keep shrinking bytes.
// ws layout: [0, 256KB) h dbuf (bf16-pair, tagged) | [0x80000, +4MB) embW fp32

#define T_STEPS 1024
#define BATCH   64
#define EDIM    256
#define HDIM    1024

typedef float    f32x4  __attribute__((ext_vector_type(4)));
typedef short    bf16x8 __attribute__((ext_vector_type(8)));
typedef uint32_t u32x4  __attribute__((ext_vector_type(4)));

__device__ __forceinline__ unsigned short f2bf(float f) {
  union { float f; uint32_t u; } v; v.f = f;
  uint32_t r = (v.u + 0x7FFFu + ((v.u >> 16) & 1u)) >> 16;  // RNE
  return (unsigned short)r;
}
__device__ __forceinline__ float sigf(float x) { return 1.f / (1.f + __expf(-x)); }
__device__ __forceinline__ float tanh_fast(float x) {
  float ax = fabsf(x);
  float e  = __expf(-2.f * ax);
  float t  = (1.f - e) / (1.f + e);
  return copysignf(t, x);
}

__global__ void __launch_bounds__(256)
embw_kernel(const float* __restrict__ emb, const float* __restrict__ W_ih,
            const float* __restrict__ b_ih, const float* __restrict__ b_hh,
            float* __restrict__ embW)
{
  __shared__ float ev[EDIM];
  const int v   = blockIdx.y;
  const int col = blockIdx.x * 256 + threadIdx.x;
  ev[threadIdx.x] = emb[v * EDIM + threadIdx.x];
  __syncthreads();
  const float4* wr = (const float4*)(W_ih + (size_t)col * EDIM);
  float acc = b_ih[col] + b_hh[col];
#pragma unroll 4
  for (int e4 = 0; e4 < EDIM / 4; ++e4) {
    const float4 q = wr[e4];
    acc += ev[4*e4+0] * q.x + ev[4*e4+1] * q.y + ev[4*e4+2] * q.z + ev[4*e4+3] * q.w;
  }
  embW[(size_t)v * (4 * HDIM) + col] = acc;
}

// 4 coherent 16B loads + in-asm drain. "+v" keeps exec-masked lanes' previous
// (fresh) values across retries. Load AND wait live in ONE asm region: no
// in-flight registers ever cross C statements (R10 lesson).
#define ISSUE4_WAIT(VOFF)                                                   \
  asm volatile(                                                             \
    "global_load_dwordx4 %0, %4, %5 sc0 sc1\n\t"                            \
    "global_load_dwordx4 %1, %4, %5 offset:64 sc0 sc1\n\t"                  \
    "global_load_dwordx4 %2, %4, %5 offset:128 sc0 sc1\n\t"                 \
    "global_load_dwordx4 %3, %4, %5 offset:192 sc0 sc1\n\t"                 \
    "s_waitcnt vmcnt(0)"                                                    \
    : "+v"(r0), "+v"(r1), "+v"(r2), "+v"(r3)                                \
    : "v"(VOFF), "s"(hbuf)                                                  \
    : "memory")

#define TCHK(R) do { o |= (R.x ^ tagw); o |= (R.y ^ tagw);                  \
                     o |= (R.z ^ tagw); o |= (R.w ^ tagw); } while (0)

// freshness sweep over the 4 result registers -> bad (per-lane, LSB only)
#define TAGCHK4() do { o = 0;                                               \
    TCHK(r0); TCHK(r1); TCHK(r2); TCHK(r3);                                 \
    bad = o & 1u; } while (0)

// LDS-only barrier: order ds ops, leave VMEM (the h store) in flight.
#define LDS_BARRIER() do {                                                  \
    asm volatile("s_waitcnt lgkmcnt(0)" ::: "memory");                      \
    __builtin_amdgcn_s_barrier();                                           \
    __builtin_amdgcn_sched_barrier(0);                                      \
  } while (0)

__global__ void __launch_bounds__(512, 1)
lstm_kernel(const int* __restrict__ tokens, const int* __restrict__ seq_len,
            const float* __restrict__ W_hh, const float* __restrict__ embW,
            uint32_t* hbuf, float* __restrict__ out)
{
  const int tid = threadIdx.x;
  const int bid = blockIdx.x;     // 0..127
  const int g   = bid & 3;        // batch group
  const int wig = bid >> 2;       // WG within group: 0..31
  const int hb  = wig << 5;       // hidden base (32 per WG)
  const int gs0 = g << 4;         // sample base (16 per group)
  const int w   = tid >> 6;       // wave 0..7 (K-split: 128 each)
  const int l   = tid & 63;
  const int lr  = l & 15;         // MFMA m / n index
  const int lq  = l >> 4;         // MFMA k-quad

  // ---- stage W_hh slice into registers as bf16 MFMA B-fragments ----
  bf16x8 bfrag[4][2][4];          // [gate][ntile][kstep] = 128 VGPRs
#pragma unroll
  for (int n = 0; n < 4; ++n)
#pragma unroll
    for (int nt = 0; nt < 2; ++nt) {
      const float* wrow = W_hh + (size_t)(n * HDIM + hb + nt * 16 + lr) * HDIM
                               + w * 128 + lq * 8;
#pragma unroll
      for (int ks = 0; ks < 4; ++ks) {
        union { bf16x8 v; unsigned short u[8]; } bu;
#pragma unroll
        for (int e = 0; e < 8; ++e) bu.u[e] = f2bf(wrow[ks * 32 + e]);
        bfrag[n][nt][ks] = bu.v;
      }
    }

  const int s  = tid >> 5;        // pointwise: sample-local 0..15
  const int j  = tid & 31;        // pointwise: hidden-local 0..31
  const int b  = gs0 + s;
  const int sl = seq_len[b];
  float c = 0.f, lastc = 0.f;

  __shared__ float part[8][4][2][16][17];  // [wave][gate][nt][m][n] pad 17 (69.6 KB)

  // bf16-pair h: lane (w,lq,lr) reads pairs (hb row gs0+lr), k-pair base
  // w*64 + lq*4, ks stride 16 pairs (=64B). A-fragment == loaded u32x4.
  const uint32_t voff_base =
      (uint32_t)(((gs0 + lr) * (HDIM / 2) + w * 64 + lq * 4) * 4);

  int tok = tokens[b];            // token for step 0

  for (int t = 0; t < T_STEPS; ++t) {
    // embW gather for step t (plain cached loads) — issued BEFORE the poll;
    // the poll's vmcnt(0) covers them -> gather hides under attempt 1.
    const float* er = embW + (size_t)tok * (4 * HDIM) + hb + j;
    float gi = er[0], gf = er[HDIM], gg = er[2 * HDIM], go = er[3 * HDIM];
    const int tnext = (t + 1 < T_STEPS) ? (t + 1) : t;
    const int tok_n = tokens[tnext * BATCH + b];

    if (t > 0) {
      const uint32_t tagw = (uint32_t)(((t - 1) >> 1) & 1);
      const uint32_t voff =
          ((uint32_t)((t - 1) & 1)) * (BATCH * (HDIM / 2) * 4u) + voff_base;
      u32x4 r0 = {0,0,0,0}, r1 = r0, r2 = r0, r3 = r0;
      uint32_t o, bad;
      ISSUE4_WAIT(voff);
      TAGCHK4();
      while (__any(bad != 0)) {
        if (bad != 0) {                    // per-lane masked retry: stale lanes only
          ISSUE4_WAIT(voff);
          TAGCHK4();
        }
      }

      // loaded u32x4 IS the bf16x8 A-fragment (tag noise ~2^-8 on half the
      // h values — accepted; threshold 6e-4, prior absmax 1.2e-4)
      f32x4 acc[4][2];
#pragma unroll
      for (int n = 0; n < 4; ++n)
#pragma unroll
        for (int nt = 0; nt < 2; ++nt)
          acc[n][nt] = (f32x4){0.f, 0.f, 0.f, 0.f};

      const u32x4 rr[4] = {r0, r1, r2, r3};
#pragma unroll
      for (int ks = 0; ks < 4; ++ks) {
        union { u32x4 u; bf16x8 v; } au;
        au.u = rr[ks];
#pragma unroll
        for (int n = 0; n < 4; ++n)
#pragma unroll
          for (int nt = 0; nt < 2; ++nt)
            acc[n][nt] = __builtin_amdgcn_mfma_f32_16x16x32_bf16(
                au.v, bfrag[n][nt][ks], acc[n][nt], 0, 0, 0);
      }
#pragma unroll
      for (int n = 0; n < 4; ++n)
#pragma unroll
        for (int nt = 0; nt < 2; ++nt)
#pragma unroll
          for (int r = 0; r < 4; ++r)   // C layout: col=lane&15, row=(lane>>4)*4+reg
            part[w][n][nt][lq * 4 + r][lr] = acc[n][nt][r];
    }

    LDS_BARRIER();                       // S1: partial writes visible (no vmcnt drain)

    if (t > 0) {
      const int ntj = j >> 4, nj = j & 15;
#pragma unroll
      for (int ww = 0; ww < 8; ++ww) {
        gi += part[ww][0][ntj][s][nj];
        gf += part[ww][1][ntj][s][nj];
        gg += part[ww][2][ntj][s][nj];
        go += part[ww][3][ntj][s][nj];
      }
    }

    const float cn = sigf(gf) * c + sigf(gi) * tanh_fast(gg);
    const float hn = sigf(go) * tanh_fast(cn);
    c = cn;
    if ((t == 0) || (t < sl)) lastc = cn;  // freeze mask (step 0 always valid)

    // h -> bf16 pair -> tagged u32 store (fire-and-forget, no drain)
    const unsigned short hu = f2bf(hn);
    const int other = __shfl_xor((int)hu, 1);
    if ((j & 1) == 0) {
      const uint32_t pk = (uint32_t)hu | ((uint32_t)(unsigned short)other << 16);
      const uint32_t tu = (pk & ~1u) | (uint32_t)((t >> 1) & 1);
      __hip_atomic_store(hbuf + (t & 1) * (BATCH * (HDIM / 2))
                              + b * (HDIM / 2) + ((hb + j) >> 1),
                         tu, __ATOMIC_RELAXED, __HIP_MEMORY_SCOPE_AGENT);
    }

    LDS_BARRIER();                       // S2: partial reads done before next writes

    tok = tok_n;
  }

  out[(size_t)b * HDIM + hb + j] = lastc;
}

extern "C" void kernel_launch(void* const* d_in, const int* in_sizes, int n_in,
                              void* d_out, int out_size, void* d_ws, size_t ws_size,
                              hipStream_t stream) {
  const int*   tokens = (const int*)d_in[0];
  const int*   seqlen = (const int*)d_in[1];
  const float* emb    = (const float*)d_in[2];
  const float* W_ih   = (const float*)d_in[3];
  const float* W_hh   = (const float*)d_in[4];
  const float* b_ih   = (const float*)d_in[5];
  const float* b_hh   = (const float*)d_in[6];
  float* out = (float*)d_out;

  uint8_t*  ws   = (uint8_t*)d_ws;
  uint32_t* hbuf = (uint32_t*)ws;               // 2 * 64*512 u32 = 256 KB
  float*    embW = (float*)(ws + 0x80000);      // 256 * 4096 fp32 = 4 MB

  // init h dbuf to 0xFF: u32 LSB=1 != first expected tag (0) for both slots
  hipMemsetAsync(ws, 0xFF, 2 * BATCH * (HDIM / 2) * 4, stream);
  embw_kernel<<<dim3(16, 256), 256, 0, stream>>>(emb, W_ih, b_ih, b_hh, embW);
  lstm_kernel<<<dim3(128), 512, 0, stream>>>(tokens, seqlen, W_hh, embW, hbuf, out);
}